// Round 1
// baseline (111.481 us; speedup 1.0000x reference)
//
#include <hip/hip_runtime.h>

#define TWO_LOG2E 2.8853900817779268f

__device__ __forceinline__ float frcp(float x) {
#if __has_builtin(__builtin_amdgcn_rcpf)
  return __builtin_amdgcn_rcpf(x);
#else
  return 1.0f / x;
#endif
}
__device__ __forceinline__ float fexp2(float x) {
#if __has_builtin(__builtin_amdgcn_exp2f)
  return __builtin_amdgcn_exp2f(x);
#else
  return exp2f(x);
#endif
}
// XOR-swizzle for transposed [k][m] staging tiles: spreads write banks, keeps
// float2/float4 read contiguity (XOR only touches bits >= 3).
__device__ __forceinline__ int swz(int k, int m, int mask) {
  return m ^ (((k >> 2) & mask) << 3);
}

// ---------------------------------------------------------------------------
// K1: A = exp(2 * query @ w1^T), B = exp(2 * key @ w2^T)
// M=4096 rows per projection, N=128, K=512. BM=32, BN=64, BK=32.
// grid (128, 2, 2), block 256. Thread tile 2x4.
// ---------------------------------------------------------------------------
__global__ __launch_bounds__(256) void k_proj_exp(
    const float* __restrict__ query, const float* __restrict__ key,
    const float* __restrict__ w1, const float* __restrict__ w2,
    float* __restrict__ Aout, float* __restrict__ Bout) {
  const float* in = blockIdx.z ? key : query;
  const float* w  = blockIdx.z ? w2  : w1;
  float* out      = blockIdx.z ? Bout : Aout;

  __shared__ float in_t[32][32];  // [k][m], swizzle mask 3
  __shared__ float w_t[32][64];   // [k][n], swizzle mask 7

  const int tid = threadIdx.x;
  const int m0g = blockIdx.x * 32;
  const int n0g = blockIdx.y * 64;
  const int tm = tid >> 4, tn = tid & 15;
  const int m0 = tm * 2, n0 = tn * 4;

  float acc[2][4] = {};
  for (int k0 = 0; k0 < 512; k0 += 32) {
    {  // stage input tile 32m x 32k, transposed (1 float4/thread)
      int m = tid >> 3, k4 = tid & 7;
      float4 a = *(const float4*)&in[(m0g + m) * 512 + k0 + k4 * 4];
      in_t[k4 * 4 + 0][swz(k4 * 4 + 0, m, 3)] = a.x;
      in_t[k4 * 4 + 1][swz(k4 * 4 + 1, m, 3)] = a.y;
      in_t[k4 * 4 + 2][swz(k4 * 4 + 2, m, 3)] = a.z;
      in_t[k4 * 4 + 3][swz(k4 * 4 + 3, m, 3)] = a.w;
    }
#pragma unroll
    for (int i = 0; i < 2; ++i) {  // stage w tile 64n x 32k, transposed
      int t = tid + i * 256;
      int n = t >> 3, k4 = t & 7;
      float4 a = *(const float4*)&w[(n0g + n) * 512 + k0 + k4 * 4];
      w_t[k4 * 4 + 0][swz(k4 * 4 + 0, n, 7)] = a.x;
      w_t[k4 * 4 + 1][swz(k4 * 4 + 1, n, 7)] = a.y;
      w_t[k4 * 4 + 2][swz(k4 * 4 + 2, n, 7)] = a.z;
      w_t[k4 * 4 + 3][swz(k4 * 4 + 3, n, 7)] = a.w;
    }
    __syncthreads();
#pragma unroll
    for (int kk = 0; kk < 32; ++kk) {
      float2 a2 = *(const float2*)&in_t[kk][swz(kk, m0, 3)];
      float4 b4 = *(const float4*)&w_t[kk][swz(kk, n0, 7)];
      acc[0][0] = fmaf(a2.x, b4.x, acc[0][0]);
      acc[0][1] = fmaf(a2.x, b4.y, acc[0][1]);
      acc[0][2] = fmaf(a2.x, b4.z, acc[0][2]);
      acc[0][3] = fmaf(a2.x, b4.w, acc[0][3]);
      acc[1][0] = fmaf(a2.y, b4.x, acc[1][0]);
      acc[1][1] = fmaf(a2.y, b4.y, acc[1][1]);
      acc[1][2] = fmaf(a2.y, b4.z, acc[1][2]);
      acc[1][3] = fmaf(a2.y, b4.w, acc[1][3]);
    }
    __syncthreads();
  }
#pragma unroll
  for (int i = 0; i < 2; ++i) {
    float4 o;
    o.x = fexp2(acc[i][0] * TWO_LOG2E);
    o.y = fexp2(acc[i][1] * TWO_LOG2E);
    o.z = fexp2(acc[i][2] * TWO_LOG2E);
    o.w = fexp2(acc[i][3] * TWO_LOG2E);
    *(float4*)&out[(m0g + m0 + i) * 128 + n0g + n0] = o;
  }
}

// ---------------------------------------------------------------------------
// K2: S[q,k] = sum_h v[h] / (A[q,h]*B[k,h] + 1);  attn = softmax_k(-2S)
// (score = sum(v) - 2S; the constant sum(v) cancels in softmax.)
// 8 q-rows per block, 4 waves, each wave owns 2 rows (lane = k within tile).
// grid (64, 8), block 256.
// ---------------------------------------------------------------------------
__global__ __launch_bounds__(256) void k_score_softmax(
    const float* __restrict__ Aexp, const float* __restrict__ Bexp,
    const float* __restrict__ vw, float* __restrict__ attn) {
  __shared__ float A_t[128][8];   // [h][q], column swizzled by ((h>>2)&3)<<1
  __shared__ float B_t[128][64];  // [h][k], column swizzled by (h>>2)&31
  __shared__ float v_s[128];

  const int tid = threadIdx.x;
  const int b = blockIdx.y;
  const int qbase = blockIdx.x * 8;
  const int qg = tid >> 6;  // wave id 0..3 -> rows qg*2, qg*2+1
  const int kl = tid & 63;  // lane = k column within a 64-wide k tile

  {  // stage A rows (8 x 128) transposed+swizzled, and v
    int ql = tid >> 5, h4 = tid & 31;
    float4 a = *(const float4*)&Aexp[(b * 512 + qbase + ql) * 128 + h4 * 4];
    int qs = ql ^ ((h4 & 3) << 1);
    A_t[h4 * 4 + 0][qs] = a.x;
    A_t[h4 * 4 + 1][qs] = a.y;
    A_t[h4 * 4 + 2][qs] = a.z;
    A_t[h4 * 4 + 3][qs] = a.w;
    if (tid < 128) v_s[tid] = vw[tid];
  }

  float S[8][2];
#pragma unroll
  for (int kt = 0; kt < 8; ++kt) {
    if (kt) __syncthreads();  // all reads of previous B_t done
#pragma unroll
    for (int i = 0; i < 8; ++i) {  // stage B tile 64k x 128h transposed+swizzled
      int t = tid + i * 256;
      int kr = t >> 5, h4 = t & 31;
      float4 bb = *(const float4*)&Bexp[(b * 512 + kt * 64 + kr) * 128 + h4 * 4];
      int ks = kr ^ h4;  // write banks: 2-way (free) instead of 32-way
      B_t[h4 * 4 + 0][ks] = bb.x;
      B_t[h4 * 4 + 1][ks] = bb.y;
      B_t[h4 * 4 + 2][ks] = bb.z;
      B_t[h4 * 4 + 3][ks] = bb.w;
    }
    __syncthreads();
    float s0 = 0.f, s1 = 0.f;
#pragma unroll 2
    for (int hg = 0; hg < 32; ++hg) {  // groups of 4 h
      int hb = hg * 4;
      float4 v4 = *(const float4*)&v_s[hb];
      int col = kl ^ hg;                      // undo B swizzle
      int aoff = (qg * 2) ^ ((hg & 3) << 1);  // undo A swizzle (keeps float2 align)
      float b0 = B_t[hb + 0][col];
      float b1 = B_t[hb + 1][col];
      float b2 = B_t[hb + 2][col];
      float b3 = B_t[hb + 3][col];
      float2 a0 = *(const float2*)&A_t[hb + 0][aoff];
      float2 a1 = *(const float2*)&A_t[hb + 1][aoff];
      float2 a2 = *(const float2*)&A_t[hb + 2][aoff];
      float2 a3 = *(const float2*)&A_t[hb + 3][aoff];
      s0 = fmaf(v4.x, frcp(fmaf(a0.x, b0, 1.0f)), s0);
      s1 = fmaf(v4.x, frcp(fmaf(a0.y, b0, 1.0f)), s1);
      s0 = fmaf(v4.y, frcp(fmaf(a1.x, b1, 1.0f)), s0);
      s1 = fmaf(v4.y, frcp(fmaf(a1.y, b1, 1.0f)), s1);
      s0 = fmaf(v4.z, frcp(fmaf(a2.x, b2, 1.0f)), s0);
      s1 = fmaf(v4.z, frcp(fmaf(a2.y, b2, 1.0f)), s1);
      s0 = fmaf(v4.w, frcp(fmaf(a3.x, b3, 1.0f)), s0);
      s1 = fmaf(v4.w, frcp(fmaf(a3.y, b3, 1.0f)), s1);
    }
    S[kt][0] = s0;
    S[kt][1] = s1;
  }

  // softmax over k of (-2S): max(score) == min(S). Rows live in one wave.
  float mn0 = S[0][0], mn1 = S[0][1];
#pragma unroll
  for (int kt = 1; kt < 8; ++kt) {
    mn0 = fminf(mn0, S[kt][0]);
    mn1 = fminf(mn1, S[kt][1]);
  }
#pragma unroll
  for (int off = 32; off > 0; off >>= 1) {
    mn0 = fminf(mn0, __shfl_xor(mn0, off));
    mn1 = fminf(mn1, __shfl_xor(mn1, off));
  }
  float sum0 = 0.f, sum1 = 0.f;
  float P0[8], P1[8];
#pragma unroll
  for (int kt = 0; kt < 8; ++kt) {
    P0[kt] = fexp2((mn0 - S[kt][0]) * TWO_LOG2E);
    P1[kt] = fexp2((mn1 - S[kt][1]) * TWO_LOG2E);
    sum0 += P0[kt];
    sum1 += P1[kt];
  }
#pragma unroll
  for (int off = 32; off > 0; off >>= 1) {
    sum0 += __shfl_xor(sum0, off);
    sum1 += __shfl_xor(sum1, off);
  }
  float r0 = frcp(sum0), r1 = frcp(sum1);
  const int row0 = (b * 512 + qbase + qg * 2) * 512;
#pragma unroll
  for (int kt = 0; kt < 8; ++kt) {
    attn[row0 + kt * 64 + kl] = P0[kt] * r0;
    attn[row0 + 512 + kt * 64 + kl] = P1[kt] * r1;
  }
}

// ---------------------------------------------------------------------------
// K3: context[b] = attn[b] (512x512) @ value[b] (512x512)
// BM=BN=64, BK=32, thread tile 4x4. grid (8, 8, 8), block 256.
// ---------------------------------------------------------------------------
__global__ __launch_bounds__(256) void k_context(
    const float* __restrict__ attn, const float* __restrict__ value,
    float* __restrict__ ctx) {
  __shared__ float at[32][64];  // [k][m] swizzled (mask 7)
  __shared__ float bt[32][64];  // [k][n] direct

  const int tid = threadIdx.x;
  const int b = blockIdx.z;
  const int m0g = blockIdx.y * 64, n0g = blockIdx.x * 64;
  const int tm = tid >> 4, tn = tid & 15;
  const int m0 = tm * 4, n0 = tn * 4;

  float acc[4][4] = {};
  for (int k0 = 0; k0 < 512; k0 += 32) {
#pragma unroll
    for (int i = 0; i < 2; ++i) {
      int t = tid + i * 256;
      int m = t >> 3, k4 = t & 7;  // attn tile 64m x 32k, transposed
      float4 av = *(const float4*)&attn[(b * 512 + m0g + m) * 512 + k0 + k4 * 4];
      at[k4 * 4 + 0][swz(k4 * 4 + 0, m, 7)] = av.x;
      at[k4 * 4 + 1][swz(k4 * 4 + 1, m, 7)] = av.y;
      at[k4 * 4 + 2][swz(k4 * 4 + 2, m, 7)] = av.z;
      at[k4 * 4 + 3][swz(k4 * 4 + 3, m, 7)] = av.w;
      int kk = t >> 4, n4 = t & 15;  // value tile 32k x 64n, direct
      *(float4*)&bt[kk][n4 * 4] =
          *(const float4*)&value[(b * 512 + k0 + kk) * 512 + n0g + n4 * 4];
    }
    __syncthreads();
#pragma unroll
    for (int kk = 0; kk < 32; ++kk) {
      float4 a4 = *(const float4*)&at[kk][swz(kk, m0, 7)];
      float4 b4 = *(const float4*)&bt[kk][n0];
      acc[0][0] = fmaf(a4.x, b4.x, acc[0][0]);
      acc[0][1] = fmaf(a4.x, b4.y, acc[0][1]);
      acc[0][2] = fmaf(a4.x, b4.z, acc[0][2]);
      acc[0][3] = fmaf(a4.x, b4.w, acc[0][3]);
      acc[1][0] = fmaf(a4.y, b4.x, acc[1][0]);
      acc[1][1] = fmaf(a4.y, b4.y, acc[1][1]);
      acc[1][2] = fmaf(a4.y, b4.z, acc[1][2]);
      acc[1][3] = fmaf(a4.y, b4.w, acc[1][3]);
      acc[2][0] = fmaf(a4.z, b4.x, acc[2][0]);
      acc[2][1] = fmaf(a4.z, b4.y, acc[2][1]);
      acc[2][2] = fmaf(a4.z, b4.z, acc[2][2]);
      acc[2][3] = fmaf(a4.z, b4.w, acc[2][3]);
      acc[3][0] = fmaf(a4.w, b4.x, acc[3][0]);
      acc[3][1] = fmaf(a4.w, b4.y, acc[3][1]);
      acc[3][2] = fmaf(a4.w, b4.z, acc[3][2]);
      acc[3][3] = fmaf(a4.w, b4.w, acc[3][3]);
    }
    __syncthreads();
  }
#pragma unroll
  for (int i = 0; i < 4; ++i) {
    float4 o = make_float4(acc[i][0], acc[i][1], acc[i][2], acc[i][3]);
    *(float4*)&ctx[(b * 512 + m0g + m0 + i) * 512 + n0g + n0] = o;
  }
}

extern "C" void kernel_launch(void* const* d_in, const int* in_sizes, int n_in,
                              void* d_out, int out_size, void* d_ws, size_t ws_size,
                              hipStream_t stream) {
  const float* query = (const float*)d_in[0];
  const float* key   = (const float*)d_in[1];
  const float* value = (const float*)d_in[2];
  const float* w1    = (const float*)d_in[3];
  const float* w2    = (const float*)d_in[4];
  const float* v     = (const float*)d_in[5];

  float* attn = (float*)d_out;             // 8*512*512
  float* ctx  = attn + 8 * 512 * 512;      // 8*512*512
  float* Aexp = (float*)d_ws;              // 4096*128
  float* Bexp = Aexp + 4096 * 128;         // 4096*128

  k_proj_exp<<<dim3(128, 2, 2), 256, 0, stream>>>(query, key, w1, w2, Aexp, Bexp);
  k_score_softmax<<<dim3(64, 8), 256, 0, stream>>>(Aexp, Bexp, v, attn);
  k_context<<<dim3(8, 8, 8), 256, 0, stream>>>(attn, value, ctx);
}

// Round 2
// 90.161 us; speedup vs baseline: 1.2365x; 1.2365x over previous
//
#include <hip/hip_runtime.h>

#define TWO_LOG2E 2.8853900817779268f

__device__ __forceinline__ float frcp(float x) {
#if __has_builtin(__builtin_amdgcn_rcpf)
  return __builtin_amdgcn_rcpf(x);
#else
  return 1.0f / x;
#endif
}
__device__ __forceinline__ float fexp2(float x) {
#if __has_builtin(__builtin_amdgcn_exp2f)
  return __builtin_amdgcn_exp2f(x);
#else
  return exp2f(x);
#endif
}
__device__ __forceinline__ unsigned short f2bf(float f) {  // RNE f32->bf16
  unsigned int u = __float_as_uint(f);
  u += 0x7fffu + ((u >> 16) & 1u);
  return (unsigned short)(u >> 16);
}
__device__ __forceinline__ unsigned int pack2bf(float lo, float hi) {
  return (unsigned int)f2bf(lo) | ((unsigned int)f2bf(hi) << 16);
}
// swizzle for f32 transposed staging tiles (K1 only)
__device__ __forceinline__ int swz(int k, int m, int mask) {
  return m ^ (((k >> 2) & mask) << 3);
}

using short8 = __attribute__((ext_vector_type(8))) short;
using f32x4v = __attribute__((ext_vector_type(4))) float;

// ---------------------------------------------------------------------------
// K1: Aexp = exp(2*query@w1^T) (f32), Bexp = exp(2*key@w2^T) (bf16)
// M=4096, N=128, K=512. BM=32, BN=64, BK=32. grid (128,2,2), block 256.
// ---------------------------------------------------------------------------
__global__ __launch_bounds__(256) void k_proj_exp(
    const float* __restrict__ query, const float* __restrict__ key,
    const float* __restrict__ w1, const float* __restrict__ w2,
    float* __restrict__ Aout, unsigned short* __restrict__ Bout) {
  const float* in = blockIdx.z ? key : query;
  const float* w  = blockIdx.z ? w2  : w1;

  __shared__ float in_t[32][32];  // [k][m], swizzle mask 3
  __shared__ float w_t[32][64];   // [k][n], swizzle mask 7

  const int tid = threadIdx.x;
  const int m0g = blockIdx.x * 32;
  const int n0g = blockIdx.y * 64;
  const int tm = tid >> 4, tn = tid & 15;
  const int m0 = tm * 2, n0 = tn * 4;

  float acc[2][4] = {};
  for (int k0 = 0; k0 < 512; k0 += 32) {
    {
      int m = tid >> 3, k4 = tid & 7;
      float4 a = *(const float4*)&in[(m0g + m) * 512 + k0 + k4 * 4];
      in_t[k4 * 4 + 0][swz(k4 * 4 + 0, m, 3)] = a.x;
      in_t[k4 * 4 + 1][swz(k4 * 4 + 1, m, 3)] = a.y;
      in_t[k4 * 4 + 2][swz(k4 * 4 + 2, m, 3)] = a.z;
      in_t[k4 * 4 + 3][swz(k4 * 4 + 3, m, 3)] = a.w;
    }
#pragma unroll
    for (int i = 0; i < 2; ++i) {
      int t = tid + i * 256;
      int n = t >> 3, k4 = t & 7;
      float4 a = *(const float4*)&w[(n0g + n) * 512 + k0 + k4 * 4];
      w_t[k4 * 4 + 0][swz(k4 * 4 + 0, n, 7)] = a.x;
      w_t[k4 * 4 + 1][swz(k4 * 4 + 1, n, 7)] = a.y;
      w_t[k4 * 4 + 2][swz(k4 * 4 + 2, n, 7)] = a.z;
      w_t[k4 * 4 + 3][swz(k4 * 4 + 3, n, 7)] = a.w;
    }
    __syncthreads();
#pragma unroll
    for (int kk = 0; kk < 32; ++kk) {
      float2 a2 = *(const float2*)&in_t[kk][swz(kk, m0, 3)];
      float4 b4 = *(const float4*)&w_t[kk][swz(kk, n0, 7)];
      acc[0][0] = fmaf(a2.x, b4.x, acc[0][0]);
      acc[0][1] = fmaf(a2.x, b4.y, acc[0][1]);
      acc[0][2] = fmaf(a2.x, b4.z, acc[0][2]);
      acc[0][3] = fmaf(a2.x, b4.w, acc[0][3]);
      acc[1][0] = fmaf(a2.y, b4.x, acc[1][0]);
      acc[1][1] = fmaf(a2.y, b4.y, acc[1][1]);
      acc[1][2] = fmaf(a2.y, b4.z, acc[1][2]);
      acc[1][3] = fmaf(a2.y, b4.w, acc[1][3]);
    }
    __syncthreads();
  }
#pragma unroll
  for (int i = 0; i < 2; ++i) {
    float4 o;
    o.x = fexp2(acc[i][0] * TWO_LOG2E);
    o.y = fexp2(acc[i][1] * TWO_LOG2E);
    o.z = fexp2(acc[i][2] * TWO_LOG2E);
    o.w = fexp2(acc[i][3] * TWO_LOG2E);
    if (blockIdx.z == 0) {
      *(float4*)&Aout[(m0g + m0 + i) * 128 + n0g + n0] = o;
    } else {
      ushort2 p0 = make_ushort2(f2bf(o.x), f2bf(o.y));
      ushort2 p1 = make_ushort2(f2bf(o.z), f2bf(o.w));
      *(uint2*)&Bout[(m0g + m0 + i) * 128 + n0g + n0] =
          make_uint2((unsigned)p0.x | ((unsigned)p0.y << 16),
                     (unsigned)p1.x | ((unsigned)p1.y << 16));
    }
  }
}

// ---------------------------------------------------------------------------
// k_valT: valT[b][n][k] = bf16(value[b][k][n]).  64x64 tiles, grid (8,8,8).
// ---------------------------------------------------------------------------
__global__ __launch_bounds__(256) void k_valT(
    const float* __restrict__ value, unsigned short* __restrict__ valT) {
  __shared__ unsigned short ts[64][66];  // pitch 66 -> bank stride 33 (odd)
  const int t = threadIdx.x;
  const int b = blockIdx.z, k0 = blockIdx.y * 64, n0 = blockIdx.x * 64;
  {
    int kr = t >> 4, n4 = (t & 15) * 4;
#pragma unroll
    for (int i = 0; i < 4; ++i) {
      float4 f = *(const float4*)&value[((b * 512) + k0 + kr + 16 * i) * 512 + n0 + n4];
      *(ushort4*)&ts[kr + 16 * i][n4] =
          make_ushort4(f2bf(f.x), f2bf(f.y), f2bf(f.z), f2bf(f.w));
    }
  }
  __syncthreads();
  {
    int nw = t >> 4, k4 = (t & 15) * 4;
#pragma unroll
    for (int i = 0; i < 4; ++i) {
      int n = nw + 16 * i;
      ushort4 o = make_ushort4(ts[k4 + 0][n], ts[k4 + 1][n], ts[k4 + 2][n], ts[k4 + 3][n]);
      *(ushort4*)&valT[((b * 512) + n0 + n) * 512 + k0 + k4] = o;
    }
  }
}

// ---------------------------------------------------------------------------
// K2: S[q,k] = sum_h v[h]/(A[q,h]*B[k,h]+1);  attn = softmax_k(-2S).
// 4 q-rows/block, 4 waves = (row-pair, k-half). k-tiles of 128 (bf16 B in LDS,
// 8B-granule XOR swizzle). Pair-2 rcp: v0/x0+v1/x1 = (v0*x1+v1*x0)/(x0*x1).
// grid (128, 8), block 256.
// ---------------------------------------------------------------------------
__global__ __launch_bounds__(256) void k_score_softmax(
    const float* __restrict__ Aexp, const unsigned short* __restrict__ Bexp,
    const float* __restrict__ vw, float* __restrict__ attn) {
  __shared__ __align__(16) char Bt_raw[128 * 256];  // [k][h] bf16, swizzled, 32KB
  __shared__ float A_s[4][128];
  __shared__ float v_s[128];
  __shared__ float red[4][2];

  const int tid = threadIdx.x;
  const int b = blockIdx.y;
  const int qbase = blockIdx.x * 4;
  const int wav = tid >> 6;
  const int lane = tid & 63;
  const int rp = wav >> 1;   // row pair 0..1
  const int kh = wav & 1;    // k half 0..1
  const int klocal = kh * 64 + lane;
  const int kx31 = klocal & 31;
  char* const bbase = Bt_raw + klocal * 256;

  if (tid < 128) {
    int q = tid >> 5, h4 = (tid & 31) * 4;
    *(float4*)&A_s[q][h4] = *(const float4*)&Aexp[(b * 512 + qbase + q) * 128 + h4];
    v_s[tid] = vw[tid];
  }

  float S0[4], S1[4];
#pragma unroll
  for (int kt = 0; kt < 4; ++kt) {
    __syncthreads();  // A_s ready / prev B reads done
    {  // stage B tile 128k x 128h bf16, transposed-free (already [k][h]), swizzled
      int kr = tid >> 1;
      int hseg = (tid & 1) * 64;
      const uint4* src = (const uint4*)&Bexp[(b * 512 + kt * 128 + kr) * 128 + hseg];
      char* dst = Bt_raw + kr * 256;
      int kk31 = kr & 31;
#pragma unroll
      for (int j = 0; j < 8; ++j) {
        uint4 vv = src[j];
        int g0 = (hseg >> 2) + 2 * j;
        *(uint2*)(dst + ((g0 ^ kk31) << 3)) = make_uint2(vv.x, vv.y);
        *(uint2*)(dst + (((g0 + 1) ^ kk31) << 3)) = make_uint2(vv.z, vv.w);
      }
    }
    __syncthreads();
    float s0 = 0.f, s1 = 0.f;
#pragma unroll
    for (int hg = 0; hg < 32; ++hg) {
      const int hb = hg * 4;
      unsigned long long u = *(const unsigned long long*)(bbase + ((hg ^ kx31) << 3));
      unsigned int lo = (unsigned int)u, hi = (unsigned int)(u >> 32);
      float b0 = __uint_as_float(lo << 16);
      float b1 = __uint_as_float(lo & 0xffff0000u);
      float b2 = __uint_as_float(hi << 16);
      float b3 = __uint_as_float(hi & 0xffff0000u);
      float4 v4 = *(const float4*)&v_s[hb];
      float4 a0 = *(const float4*)&A_s[rp * 2 + 0][hb];
      float4 a1 = *(const float4*)&A_s[rp * 2 + 1][hb];
      {
        float x0 = fmaf(a0.x, b0, 1.f), x1 = fmaf(a0.y, b1, 1.f);
        float n01 = fmaf(v4.y, x0, v4.x * x1);
        s0 = fmaf(n01, frcp(x0 * x1), s0);
        float x2 = fmaf(a0.z, b2, 1.f), x3 = fmaf(a0.w, b3, 1.f);
        float n23 = fmaf(v4.w, x2, v4.z * x3);
        s0 = fmaf(n23, frcp(x2 * x3), s0);
      }
      {
        float x0 = fmaf(a1.x, b0, 1.f), x1 = fmaf(a1.y, b1, 1.f);
        float n01 = fmaf(v4.y, x0, v4.x * x1);
        s1 = fmaf(n01, frcp(x0 * x1), s1);
        float x2 = fmaf(a1.z, b2, 1.f), x3 = fmaf(a1.w, b3, 1.f);
        float n23 = fmaf(v4.w, x2, v4.z * x3);
        s1 = fmaf(n23, frcp(x2 * x3), s1);
      }
    }
    S0[kt] = s0;
    S1[kt] = s1;
  }

  // softmax over k of (-2S): max(score) <-> min(S). Rows span 2 waves (k-halves).
  float mn0 = fminf(fminf(S0[0], S0[1]), fminf(S0[2], S0[3]));
  float mn1 = fminf(fminf(S1[0], S1[1]), fminf(S1[2], S1[3]));
#pragma unroll
  for (int off = 32; off > 0; off >>= 1) {
    mn0 = fminf(mn0, __shfl_xor(mn0, off));
    mn1 = fminf(mn1, __shfl_xor(mn1, off));
  }
  if (lane == 0) { red[wav][0] = mn0; red[wav][1] = mn1; }
  __syncthreads();
  mn0 = fminf(red[wav][0], red[wav ^ 1][0]);
  mn1 = fminf(red[wav][1], red[wav ^ 1][1]);
  __syncthreads();  // before red reuse

  float P0[4], P1[4];
  float sum0 = 0.f, sum1 = 0.f;
#pragma unroll
  for (int kt = 0; kt < 4; ++kt) {
    P0[kt] = fexp2((mn0 - S0[kt]) * TWO_LOG2E);
    P1[kt] = fexp2((mn1 - S1[kt]) * TWO_LOG2E);
    sum0 += P0[kt];
    sum1 += P1[kt];
  }
#pragma unroll
  for (int off = 32; off > 0; off >>= 1) {
    sum0 += __shfl_xor(sum0, off);
    sum1 += __shfl_xor(sum1, off);
  }
  if (lane == 0) { red[wav][0] = sum0; red[wav][1] = sum1; }
  __syncthreads();
  float r0 = frcp(red[wav][0] + red[wav ^ 1][0]);
  float r1 = frcp(red[wav][1] + red[wav ^ 1][1]);

  const int row0 = (b * 512 + qbase + rp * 2) * 512;
#pragma unroll
  for (int kt = 0; kt < 4; ++kt) {
    int kcol = kt * 128 + kh * 64 + lane;
    attn[row0 + kcol] = P0[kt] * r0;
    attn[row0 + 512 + kcol] = P1[kt] * r1;
  }
}

// ---------------------------------------------------------------------------
// K3: context[b] = attn[b] @ value[b] via bf16 MFMA 16x16x32.
// Tile 64x64, BK=64, 4 waves (2x2), wave tile 32x32 (2x2 frags).
// A = attn (f32 -> bf16 in staging), B^T = valT (bf16). XOR-swizzled LDS.
// grid (8,8,8), block 256.
// ---------------------------------------------------------------------------
__global__ __launch_bounds__(256) void k_context_mfma(
    const float* __restrict__ attn, const unsigned short* __restrict__ valT,
    float* __restrict__ ctx) {
  __shared__ __align__(16) char At[64 * 128];  // [m][k] bf16 swizzled, 8KB
  __shared__ __align__(16) char Bt[64 * 128];  // [n][k] bf16 swizzled, 8KB

  const int t = threadIdx.x;
  const int b = blockIdx.z;
  const int m0 = blockIdx.y * 64, n0 = blockIdx.x * 64;
  const int w = t >> 6, l = t & 63;
  const int wr = w >> 1, wc = w & 1;

  f32x4v acc[2][2];
  acc[0][0] = 0; acc[0][1] = 0; acc[1][0] = 0; acc[1][1] = 0;

  const int sr = t >> 2;           // staging row 0..63
  const int sg = (t & 3);          // granule base
  const int sswz = sr & 7;

  for (int k0 = 0; k0 < 512; k0 += 64) {
    if (k0) __syncthreads();
    {  // stage A: 16 f32 -> 16 bf16 per thread
      const float* src = &attn[(b * 512 + m0 + sr) * 512 + k0 + sg * 16];
      char* dst = At + sr * 128;
#pragma unroll
      for (int h = 0; h < 2; ++h) {
        float4 f0 = *(const float4*)(src + h * 8);
        float4 f1 = *(const float4*)(src + h * 8 + 4);
        uint4 p = make_uint4(pack2bf(f0.x, f0.y), pack2bf(f0.z, f0.w),
                             pack2bf(f1.x, f1.y), pack2bf(f1.z, f1.w));
        int g = sg * 2 + h;
        *(uint4*)(dst + ((g ^ sswz) << 4)) = p;
      }
      // stage B^T: 32 bf16 per thread (already bf16)
      const unsigned short* srcb = &valT[(b * 512 + n0 + sr) * 512 + k0];
      char* dstb = Bt + sr * 128;
#pragma unroll
      for (int h = 0; h < 2; ++h) {
        int g = sg + h * 4;
        uint4 vb = *(const uint4*)(srcb + g * 8);
        *(uint4*)(dstb + ((g ^ sswz) << 4)) = vb;
      }
    }
    __syncthreads();
#pragma unroll
    for (int ks = 0; ks < 2; ++ks) {
      const int gb = ks * 4 + (l >> 4);
      short8 af[2], bf_[2];
#pragma unroll
      for (int mi = 0; mi < 2; ++mi) {
        int ra = wr * 32 + mi * 16 + (l & 15);
        af[mi] = *(const short8*)(At + ra * 128 + ((gb ^ (ra & 7)) << 4));
      }
#pragma unroll
      for (int ni = 0; ni < 2; ++ni) {
        int rb = wc * 32 + ni * 16 + (l & 15);
        bf_[ni] = *(const short8*)(Bt + rb * 128 + ((gb ^ (rb & 7)) << 4));
      }
#pragma unroll
      for (int mi = 0; mi < 2; ++mi)
#pragma unroll
        for (int ni = 0; ni < 2; ++ni)
          acc[mi][ni] = __builtin_amdgcn_mfma_f32_16x16x32_bf16(
              af[mi], bf_[ni], acc[mi][ni], 0, 0, 0);
    }
  }
  __syncthreads();
#pragma unroll
  for (int mi = 0; mi < 2; ++mi)
#pragma unroll
    for (int ni = 0; ni < 2; ++ni) {
      int col = n0 + wc * 32 + ni * 16 + (l & 15);
#pragma unroll
      for (int j = 0; j < 4; ++j) {
        int row = m0 + wr * 32 + mi * 16 + (l >> 4) * 4 + j;
        ctx[(b * 512 + row) * 512 + col] = acc[mi][ni][j];
      }
    }
}

extern "C" void kernel_launch(void* const* d_in, const int* in_sizes, int n_in,
                              void* d_out, int out_size, void* d_ws, size_t ws_size,
                              hipStream_t stream) {
  const float* query = (const float*)d_in[0];
  const float* key   = (const float*)d_in[1];
  const float* value = (const float*)d_in[2];
  const float* w1    = (const float*)d_in[3];
  const float* w2    = (const float*)d_in[4];
  const float* v     = (const float*)d_in[5];

  float* attn = (float*)d_out;
  float* ctx  = attn + 8 * 512 * 512;

  float* Aexp = (float*)d_ws;                              // 4096*128 f32 (2MB)
  unsigned short* Bexp = (unsigned short*)(Aexp + 4096 * 128);  // 4096*128 bf16 (1MB)
  unsigned short* valT = Bexp + 4096 * 128;                // 8*512*512 bf16 (4MB)

  k_proj_exp<<<dim3(128, 2, 2), 256, 0, stream>>>(query, key, w1, w2, Aexp, Bexp);
  k_valT<<<dim3(8, 8, 8), 256, 0, stream>>>(value, valT);
  k_score_softmax<<<dim3(128, 8), 256, 0, stream>>>(Aexp, Bexp, v, attn);
  k_context_mfma<<<dim3(8, 8, 8), 256, 0, stream>>>(attn, valT, ctx);
}

// Round 3
// 72.081 us; speedup vs baseline: 1.5466x; 1.2508x over previous
//
#include <hip/hip_runtime.h>

#define TWO_LOG2E 2.8853900817779268f

__device__ __forceinline__ float frcp(float x) {
#if __has_builtin(__builtin_amdgcn_rcpf)
  return __builtin_amdgcn_rcpf(x);
#else
  return 1.0f / x;
#endif
}
__device__ __forceinline__ float fexp2(float x) {
#if __has_builtin(__builtin_amdgcn_exp2f)
  return __builtin_amdgcn_exp2f(x);
#else
  return exp2f(x);
#endif
}
__device__ __forceinline__ unsigned short f2bf(float f) {  // RNE f32->bf16
  unsigned int u = __float_as_uint(f);
  u += 0x7fffu + ((u >> 16) & 1u);
  return (unsigned short)(u >> 16);
}
__device__ __forceinline__ unsigned int pack2bf(float lo, float hi) {
  return (unsigned int)f2bf(lo) | ((unsigned int)f2bf(hi) << 16);
}

using short8 = __attribute__((ext_vector_type(8))) short;
using f32x4v = __attribute__((ext_vector_type(4))) float;

// ---------------------------------------------------------------------------
// K1: Aexp = exp(2*query@w1^T) (f32), Bexp = exp(2*key@w2^T) (bf16)
// via bf16 MFMA 16x16x32. M=4096, N=128, K=512. BM=32, BN=64, BK=64.
// grid (128, 2, 2), block 256 (4 waves: wr = m-half(16), wc = n-half(32)).
// ---------------------------------------------------------------------------
__global__ __launch_bounds__(256) void k_proj_mfma(
    const float* __restrict__ query, const float* __restrict__ key,
    const float* __restrict__ w1, const float* __restrict__ w2,
    float* __restrict__ Aout, unsigned short* __restrict__ Bout) {
  const float* in = blockIdx.z ? key : query;
  const float* wm = blockIdx.z ? w2  : w1;

  __shared__ __align__(16) char Abuf[32 * 128];  // [m][k] bf16, swizzled, 4KB
  __shared__ __align__(16) char Bbuf[64 * 128];  // [n][k] bf16, swizzled, 8KB

  const int t = threadIdx.x;
  const int m0g = blockIdx.x * 32;
  const int n0g = blockIdx.y * 64;
  const int w = t >> 6, l = t & 63;
  const int wr = w >> 1, wc = w & 1;

  f32x4v acc[2];
  acc[0] = 0;
  acc[1] = 0;

  const int srow = t >> 3, sg = t & 7;  // staging: row, granule

  for (int k0 = 0; k0 < 512; k0 += 64) {
    if (k0) __syncthreads();
    {  // stage A tile 32m x 64k: 1 granule (8 floats -> 8 bf16) per thread
      const float* src = &in[(m0g + srow) * 512 + k0 + sg * 8];
      float4 f0 = *(const float4*)src;
      float4 f1 = *(const float4*)(src + 4);
      uint4 p = make_uint4(pack2bf(f0.x, f0.y), pack2bf(f0.z, f0.w),
                           pack2bf(f1.x, f1.y), pack2bf(f1.z, f1.w));
      *(uint4*)(Abuf + srow * 128 + ((sg ^ (srow & 7)) << 4)) = p;
    }
#pragma unroll
    for (int i = 0; i < 2; ++i) {  // stage B(w) tile 64n x 64k: 2 granules/thread
      int row = srow + 32 * i;
      const float* src = &wm[(n0g + row) * 512 + k0 + sg * 8];
      float4 f0 = *(const float4*)src;
      float4 f1 = *(const float4*)(src + 4);
      uint4 p = make_uint4(pack2bf(f0.x, f0.y), pack2bf(f0.z, f0.w),
                           pack2bf(f1.x, f1.y), pack2bf(f1.z, f1.w));
      *(uint4*)(Bbuf + row * 128 + ((sg ^ (row & 7)) << 4)) = p;
    }
    __syncthreads();
#pragma unroll
    for (int ks = 0; ks < 2; ++ks) {
      const int gb = ks * 4 + (l >> 4);
      int ra = wr * 16 + (l & 15);
      short8 af = *(const short8*)(Abuf + ra * 128 + ((gb ^ (ra & 7)) << 4));
#pragma unroll
      for (int ni = 0; ni < 2; ++ni) {
        int rb = wc * 32 + ni * 16 + (l & 15);
        short8 bf_ = *(const short8*)(Bbuf + rb * 128 + ((gb ^ (rb & 7)) << 4));
        acc[ni] = __builtin_amdgcn_mfma_f32_16x16x32_bf16(af, bf_, acc[ni], 0, 0, 0);
      }
    }
  }
#pragma unroll
  for (int ni = 0; ni < 2; ++ni) {
    int col = n0g + wc * 32 + ni * 16 + (l & 15);
#pragma unroll
    for (int j = 0; j < 4; ++j) {
      int row = m0g + wr * 16 + (l >> 4) * 4 + j;
      float val = fexp2(acc[ni][j] * TWO_LOG2E);
      if (blockIdx.z == 0)
        Aout[row * 128 + col] = val;
      else
        Bout[row * 128 + col] = f2bf(val);
    }
  }
}

// ---------------------------------------------------------------------------
// k_valT: valT[b][n][k] = bf16(value[b][k][n]).  64x64 tiles, grid (8,8,8).
// ---------------------------------------------------------------------------
__global__ __launch_bounds__(256) void k_valT(
    const float* __restrict__ value, unsigned short* __restrict__ valT) {
  __shared__ unsigned short ts[64][66];
  const int t = threadIdx.x;
  const int b = blockIdx.z, k0 = blockIdx.y * 64, n0 = blockIdx.x * 64;
  {
    int kr = t >> 4, n4 = (t & 15) * 4;
#pragma unroll
    for (int i = 0; i < 4; ++i) {
      float4 f = *(const float4*)&value[((b * 512) + k0 + kr + 16 * i) * 512 + n0 + n4];
      *(ushort4*)&ts[kr + 16 * i][n4] =
          make_ushort4(f2bf(f.x), f2bf(f.y), f2bf(f.z), f2bf(f.w));
    }
  }
  __syncthreads();
  {
    int nw = t >> 4, k4 = (t & 15) * 4;
#pragma unroll
    for (int i = 0; i < 4; ++i) {
      int n = nw + 16 * i;
      ushort4 o = make_ushort4(ts[k4 + 0][n], ts[k4 + 1][n], ts[k4 + 2][n], ts[k4 + 3][n]);
      *(ushort4*)&valT[((b * 512) + n0 + n) * 512 + k0 + k4] = o;
    }
  }
}

// ---------------------------------------------------------------------------
// K2: S[q,k] = sum_h v[h]/(A[q,h]*B[k,h]+1);  attn = softmax_k(-2S).
// A and v are WAVE-UNIFORM -> scalar loads (s_load) via readfirstlane; only B
// (per-lane k-column) lives in LDS (bf16, 8B-granule XOR swizzle).
// 4 q-rows/block, 4 waves = (row-pair, k-half). grid (128, 8), block 256.
// ---------------------------------------------------------------------------
__global__ __launch_bounds__(256) void k_score_softmax(
    const float* __restrict__ Aexp, const unsigned short* __restrict__ Bexp,
    const float* __restrict__ vw, float* __restrict__ attn) {
  __shared__ __align__(16) char Bt_raw[128 * 256];  // [k][h] bf16, swizzled, 32KB
  __shared__ float red[4][2];

  const int tid = threadIdx.x;
  const int b = blockIdx.y;
  const int qbase = blockIdx.x * 4;
  const int wav = tid >> 6;
  const int lane = tid & 63;
  const int rp = wav >> 1;   // row pair 0..1
  const int kh = wav & 1;    // k half 0..1
  const int klocal = kh * 64 + lane;
  const int kx31 = klocal & 31;
  char* const bbase = Bt_raw + klocal * 256;

  // wave-uniform bases for scalar loads of A rows and v
  const int rf0 = __builtin_amdgcn_readfirstlane((b * 512 + qbase + rp * 2) * 128);
  const float4* const ar0 = (const float4*)(Aexp + rf0);
  const float4* const ar1 = ar0 + 32;  // next row (+128 floats)
  const float4* const vv4 = (const float4*)vw;

  float S0[4], S1[4];
#pragma unroll
  for (int kt = 0; kt < 4; ++kt) {
    __syncthreads();  // prev B reads done
    {  // stage B tile 128k x 128h bf16 (already [k][h]), swizzled
      int kr = tid >> 1;
      int hseg = (tid & 1) * 64;
      const uint4* src = (const uint4*)&Bexp[(b * 512 + kt * 128 + kr) * 128 + hseg];
      char* dst = Bt_raw + kr * 256;
      int kk31 = kr & 31;
#pragma unroll
      for (int j = 0; j < 8; ++j) {
        uint4 vv = src[j];
        int g0 = (hseg >> 2) + 2 * j;
        *(uint2*)(dst + ((g0 ^ kk31) << 3)) = make_uint2(vv.x, vv.y);
        *(uint2*)(dst + (((g0 + 1) ^ kk31) << 3)) = make_uint2(vv.z, vv.w);
      }
    }
    __syncthreads();
    float s0 = 0.f, s1 = 0.f;
#pragma unroll 4
    for (int hg = 0; hg < 32; ++hg) {
      unsigned long long u = *(const unsigned long long*)(bbase + ((hg ^ kx31) << 3));
      float4 v4 = vv4[hg];  // scalar (uniform)
      float4 a0 = ar0[hg];  // scalar (uniform)
      float4 a1 = ar1[hg];  // scalar (uniform)
      unsigned int lo = (unsigned int)u, hi = (unsigned int)(u >> 32);
      float b0 = __uint_as_float(lo << 16);
      float b1 = __uint_as_float(lo & 0xffff0000u);
      float b2 = __uint_as_float(hi << 16);
      float b3 = __uint_as_float(hi & 0xffff0000u);
      {
        float x0 = fmaf(a0.x, b0, 1.f), x1 = fmaf(a0.y, b1, 1.f);
        float n01 = fmaf(v4.y, x0, v4.x * x1);
        s0 = fmaf(n01, frcp(x0 * x1), s0);
        float x2 = fmaf(a0.z, b2, 1.f), x3 = fmaf(a0.w, b3, 1.f);
        float n23 = fmaf(v4.w, x2, v4.z * x3);
        s0 = fmaf(n23, frcp(x2 * x3), s0);
      }
      {
        float x0 = fmaf(a1.x, b0, 1.f), x1 = fmaf(a1.y, b1, 1.f);
        float n01 = fmaf(v4.y, x0, v4.x * x1);
        s1 = fmaf(n01, frcp(x0 * x1), s1);
        float x2 = fmaf(a1.z, b2, 1.f), x3 = fmaf(a1.w, b3, 1.f);
        float n23 = fmaf(v4.w, x2, v4.z * x3);
        s1 = fmaf(n23, frcp(x2 * x3), s1);
      }
    }
    S0[kt] = s0;
    S1[kt] = s1;
  }

  // softmax over k of (-2S): max(score) <-> min(S). Rows span 2 waves (k-halves).
  float mn0 = fminf(fminf(S0[0], S0[1]), fminf(S0[2], S0[3]));
  float mn1 = fminf(fminf(S1[0], S1[1]), fminf(S1[2], S1[3]));
#pragma unroll
  for (int off = 32; off > 0; off >>= 1) {
    mn0 = fminf(mn0, __shfl_xor(mn0, off));
    mn1 = fminf(mn1, __shfl_xor(mn1, off));
  }
  if (lane == 0) { red[wav][0] = mn0; red[wav][1] = mn1; }
  __syncthreads();
  mn0 = fminf(red[wav][0], red[wav ^ 1][0]);
  mn1 = fminf(red[wav][1], red[wav ^ 1][1]);
  __syncthreads();  // before red reuse

  float P0[4], P1[4];
  float sum0 = 0.f, sum1 = 0.f;
#pragma unroll
  for (int kt = 0; kt < 4; ++kt) {
    P0[kt] = fexp2((mn0 - S0[kt]) * TWO_LOG2E);
    P1[kt] = fexp2((mn1 - S1[kt]) * TWO_LOG2E);
    sum0 += P0[kt];
    sum1 += P1[kt];
  }
#pragma unroll
  for (int off = 32; off > 0; off >>= 1) {
    sum0 += __shfl_xor(sum0, off);
    sum1 += __shfl_xor(sum1, off);
  }
  if (lane == 0) { red[wav][0] = sum0; red[wav][1] = sum1; }
  __syncthreads();
  float r0 = frcp(red[wav][0] + red[wav ^ 1][0]);
  float r1 = frcp(red[wav][1] + red[wav ^ 1][1]);

  const int row0 = (b * 512 + qbase + rp * 2) * 512;
#pragma unroll
  for (int kt = 0; kt < 4; ++kt) {
    int kcol = kt * 128 + kh * 64 + lane;
    attn[row0 + kcol] = P0[kt] * r0;
    attn[row0 + 512 + kcol] = P1[kt] * r1;
  }
}

// ---------------------------------------------------------------------------
// K3: context[b] = attn[b] @ value[b] via bf16 MFMA 16x16x32.
// Tile 64x64, BK=64, 4 waves (2x2), wave tile 32x32 (2x2 frags).
// grid (8,8,8), block 256.
// ---------------------------------------------------------------------------
__global__ __launch_bounds__(256) void k_context_mfma(
    const float* __restrict__ attn, const unsigned short* __restrict__ valT,
    float* __restrict__ ctx) {
  __shared__ __align__(16) char At[64 * 128];  // [m][k] bf16 swizzled, 8KB
  __shared__ __align__(16) char Bt[64 * 128];  // [n][k] bf16 swizzled, 8KB

  const int t = threadIdx.x;
  const int b = blockIdx.z;
  const int m0 = blockIdx.y * 64, n0 = blockIdx.x * 64;
  const int w = t >> 6, l = t & 63;
  const int wr = w >> 1, wc = w & 1;

  f32x4v acc[2][2];
  acc[0][0] = 0; acc[0][1] = 0; acc[1][0] = 0; acc[1][1] = 0;

  const int sr = t >> 2;
  const int sg = (t & 3);
  const int sswz = sr & 7;

  for (int k0 = 0; k0 < 512; k0 += 64) {
    if (k0) __syncthreads();
    {  // stage A: 16 f32 -> 16 bf16 per thread
      const float* src = &attn[(b * 512 + m0 + sr) * 512 + k0 + sg * 16];
      char* dst = At + sr * 128;
#pragma unroll
      for (int h = 0; h < 2; ++h) {
        float4 f0 = *(const float4*)(src + h * 8);
        float4 f1 = *(const float4*)(src + h * 8 + 4);
        uint4 p = make_uint4(pack2bf(f0.x, f0.y), pack2bf(f0.z, f0.w),
                             pack2bf(f1.x, f1.y), pack2bf(f1.z, f1.w));
        int g = sg * 2 + h;
        *(uint4*)(dst + ((g ^ sswz) << 4)) = p;
      }
      // stage B^T: 32 bf16 per thread (already bf16)
      const unsigned short* srcb = &valT[(b * 512 + n0 + sr) * 512 + k0];
      char* dstb = Bt + sr * 128;
#pragma unroll
      for (int h = 0; h < 2; ++h) {
        int g = sg + h * 4;
        uint4 vb = *(const uint4*)(srcb + g * 8);
        *(uint4*)(dstb + ((g ^ sswz) << 4)) = vb;
      }
    }
    __syncthreads();
#pragma unroll
    for (int ks = 0; ks < 2; ++ks) {
      const int gb = ks * 4 + (l >> 4);
      short8 af[2], bf_[2];
#pragma unroll
      for (int mi = 0; mi < 2; ++mi) {
        int ra = wr * 32 + mi * 16 + (l & 15);
        af[mi] = *(const short8*)(At + ra * 128 + ((gb ^ (ra & 7)) << 4));
      }
#pragma unroll
      for (int ni = 0; ni < 2; ++ni) {
        int rb = wc * 32 + ni * 16 + (l & 15);
        bf_[ni] = *(const short8*)(Bt + rb * 128 + ((gb ^ (rb & 7)) << 4));
      }
#pragma unroll
      for (int mi = 0; mi < 2; ++mi)
#pragma unroll
        for (int ni = 0; ni < 2; ++ni)
          acc[mi][ni] = __builtin_amdgcn_mfma_f32_16x16x32_bf16(
              af[mi], bf_[ni], acc[mi][ni], 0, 0, 0);
    }
  }
  __syncthreads();
#pragma unroll
  for (int mi = 0; mi < 2; ++mi)
#pragma unroll
    for (int ni = 0; ni < 2; ++ni) {
      int col = n0 + wc * 32 + ni * 16 + (l & 15);
#pragma unroll
      for (int j = 0; j < 4; ++j) {
        int row = m0 + wr * 32 + mi * 16 + (l >> 4) * 4 + j;
        ctx[(b * 512 + row) * 512 + col] = acc[mi][ni][j];
      }
    }
}

extern "C" void kernel_launch(void* const* d_in, const int* in_sizes, int n_in,
                              void* d_out, int out_size, void* d_ws, size_t ws_size,
                              hipStream_t stream) {
  const float* query = (const float*)d_in[0];
  const float* key   = (const float*)d_in[1];
  const float* value = (const float*)d_in[2];
  const float* w1    = (const float*)d_in[3];
  const float* w2    = (const float*)d_in[4];
  const float* v     = (const float*)d_in[5];

  float* attn = (float*)d_out;
  float* ctx  = attn + 8 * 512 * 512;

  float* Aexp = (float*)d_ws;                                   // 4096*128 f32
  unsigned short* Bexp = (unsigned short*)(Aexp + 4096 * 128);  // 4096*128 bf16
  unsigned short* valT = Bexp + 4096 * 128;                     // 8*512*512 bf16

  k_proj_mfma<<<dim3(128, 2, 2), 256, 0, stream>>>(query, key, w1, w2, Aexp, Bexp);
  k_valT<<<dim3(8, 8, 8), 256, 0, stream>>>(value, valT);
  k_score_softmax<<<dim3(128, 8), 256, 0, stream>>>(Aexp, Bexp, v, attn);
  k_context_mfma<<<dim3(8, 8, 8), 256, 0, stream>>>(attn, valT, ctx);
}

// Round 4
// 71.520 us; speedup vs baseline: 1.5587x; 1.0078x over previous
//
#include <hip/hip_runtime.h>

#define TWO_LOG2E 2.8853900817779268f

__device__ __forceinline__ float frcp(float x) {
#if __has_builtin(__builtin_amdgcn_rcpf)
  return __builtin_amdgcn_rcpf(x);
#else
  return 1.0f / x;
#endif
}
__device__ __forceinline__ float fexp2(float x) {
#if __has_builtin(__builtin_amdgcn_exp2f)
  return __builtin_amdgcn_exp2f(x);
#else
  return exp2f(x);
#endif
}
__device__ __forceinline__ unsigned short f2bf(float f) {  // RNE f32->bf16
  unsigned int u = __float_as_uint(f);
  u += 0x7fffu + ((u >> 16) & 1u);
  return (unsigned short)(u >> 16);
}
__device__ __forceinline__ unsigned int pack2bf(float lo, float hi) {
  return (unsigned int)f2bf(lo) | ((unsigned int)f2bf(hi) << 16);
}

using short8 = __attribute__((ext_vector_type(8))) short;
using f32x4v = __attribute__((ext_vector_type(4))) float;

// ---------------------------------------------------------------------------
// K1: Aexp = exp(2*query@w1^T) (f32), Bexp = exp(2*key@w2^T) (bf16)
// via bf16 MFMA 16x16x32. M=4096, N=128, K=512. BM=32, BN=64, BK=64.
// grid (128, 2, 2), block 256 (4 waves: wr = m-half(16), wc = n-half(32)).
// ---------------------------------------------------------------------------
__global__ __launch_bounds__(256) void k_proj_mfma(
    const float* __restrict__ query, const float* __restrict__ key,
    const float* __restrict__ w1, const float* __restrict__ w2,
    float* __restrict__ Aout, unsigned short* __restrict__ Bout) {
  const float* in = blockIdx.z ? key : query;
  const float* wm = blockIdx.z ? w2  : w1;

  __shared__ __align__(16) char Abuf[32 * 128];  // [m][k] bf16, swizzled, 4KB
  __shared__ __align__(16) char Bbuf[64 * 128];  // [n][k] bf16, swizzled, 8KB

  const int t = threadIdx.x;
  const int m0g = blockIdx.x * 32;
  const int n0g = blockIdx.y * 64;
  const int w = t >> 6, l = t & 63;
  const int wr = w >> 1, wc = w & 1;

  f32x4v acc[2];
  acc[0] = 0;
  acc[1] = 0;

  const int srow = t >> 3, sg = t & 7;  // staging: row, granule

  for (int k0 = 0; k0 < 512; k0 += 64) {
    if (k0) __syncthreads();
    {  // stage A tile 32m x 64k: 1 granule (8 floats -> 8 bf16) per thread
      const float* src = &in[(m0g + srow) * 512 + k0 + sg * 8];
      float4 f0 = *(const float4*)src;
      float4 f1 = *(const float4*)(src + 4);
      uint4 p = make_uint4(pack2bf(f0.x, f0.y), pack2bf(f0.z, f0.w),
                           pack2bf(f1.x, f1.y), pack2bf(f1.z, f1.w));
      *(uint4*)(Abuf + srow * 128 + ((sg ^ (srow & 7)) << 4)) = p;
    }
#pragma unroll
    for (int i = 0; i < 2; ++i) {  // stage B(w) tile 64n x 64k: 2 granules/thread
      int row = srow + 32 * i;
      const float* src = &wm[(n0g + row) * 512 + k0 + sg * 8];
      float4 f0 = *(const float4*)src;
      float4 f1 = *(const float4*)(src + 4);
      uint4 p = make_uint4(pack2bf(f0.x, f0.y), pack2bf(f0.z, f0.w),
                           pack2bf(f1.x, f1.y), pack2bf(f1.z, f1.w));
      *(uint4*)(Bbuf + row * 128 + ((sg ^ (row & 7)) << 4)) = p;
    }
    __syncthreads();
#pragma unroll
    for (int ks = 0; ks < 2; ++ks) {
      const int gb = ks * 4 + (l >> 4);
      int ra = wr * 16 + (l & 15);
      short8 af = *(const short8*)(Abuf + ra * 128 + ((gb ^ (ra & 7)) << 4));
#pragma unroll
      for (int ni = 0; ni < 2; ++ni) {
        int rb = wc * 32 + ni * 16 + (l & 15);
        short8 bf_ = *(const short8*)(Bbuf + rb * 128 + ((gb ^ (rb & 7)) << 4));
        acc[ni] = __builtin_amdgcn_mfma_f32_16x16x32_bf16(af, bf_, acc[ni], 0, 0, 0);
      }
    }
  }
#pragma unroll
  for (int ni = 0; ni < 2; ++ni) {
    int col = n0g + wc * 32 + ni * 16 + (l & 15);
#pragma unroll
    for (int j = 0; j < 4; ++j) {
      int row = m0g + wr * 16 + (l >> 4) * 4 + j;
      float val = fexp2(acc[ni][j] * TWO_LOG2E);
      if (blockIdx.z == 0)
        Aout[row * 128 + col] = val;
      else
        Bout[row * 128 + col] = f2bf(val);
    }
  }
}

// ---------------------------------------------------------------------------
// k_valT: valT[b][n][k] = bf16(value[b][k][n]).  64x64 tiles, grid (8,8,8).
// ---------------------------------------------------------------------------
__global__ __launch_bounds__(256) void k_valT(
    const float* __restrict__ value, unsigned short* __restrict__ valT) {
  __shared__ unsigned short ts[64][66];
  const int t = threadIdx.x;
  const int b = blockIdx.z, k0 = blockIdx.y * 64, n0 = blockIdx.x * 64;
  {
    int kr = t >> 4, n4 = (t & 15) * 4;
#pragma unroll
    for (int i = 0; i < 4; ++i) {
      float4 f = *(const float4*)&value[((b * 512) + k0 + kr + 16 * i) * 512 + n0 + n4];
      *(ushort4*)&ts[kr + 16 * i][n4] =
          make_ushort4(f2bf(f.x), f2bf(f.y), f2bf(f.z), f2bf(f.w));
    }
  }
  __syncthreads();
  {
    int nw = t >> 4, k4 = (t & 15) * 4;
#pragma unroll
    for (int i = 0; i < 4; ++i) {
      int n = nw + 16 * i;
      ushort4 o = make_ushort4(ts[k4 + 0][n], ts[k4 + 1][n], ts[k4 + 2][n], ts[k4 + 3][n]);
      *(ushort4*)&valT[((b * 512) + n0 + n) * 512 + k0 + k4] = o;
    }
  }
}

// ---------------------------------------------------------------------------
// K2: S[q,k] = sum_h v[h]/(A[q,h]*B[k,h]+1);  attn = softmax_k(-2S).
// A,v wave-uniform -> s_load; B (per-lane k) in LDS bf16, XOR-swizzled.
// T14 pipeline: global loads for tile kt+1 issued before computing tile kt;
// ds_write after barrier. Pair-4 rcp: one v_rcp per 4 h-terms.
// 4 q-rows/block, 4 waves = (row-pair, k-half). grid (128, 8), block 256.
// ---------------------------------------------------------------------------
__global__ __launch_bounds__(256) void k_score_softmax(
    const float* __restrict__ Aexp, const unsigned short* __restrict__ Bexp,
    const float* __restrict__ vw, float* __restrict__ attn) {
  __shared__ __align__(16) char Bt_raw[128 * 256];  // [k][h] bf16, swizzled, 32KB
  __shared__ float red[4][2];

  const int tid = threadIdx.x;
  const int b = blockIdx.y;
  const int qbase = blockIdx.x * 4;
  const int wav = tid >> 6;
  const int lane = tid & 63;
  const int rp = wav >> 1;   // row pair 0..1
  const int kh = wav & 1;    // k half 0..1
  const int klocal = kh * 64 + lane;
  // read addressing: base with lane-swizzle folded in; per-hg addr = roff0 ^ (hg<<3)
  const int roff0 = klocal * 256 + ((klocal & 31) << 3);

  // staging addressing (write side): row kr, h-segment hseg
  const int kr = tid >> 1;
  const int hseg = (tid & 1) * 64;
  const int woff0 = kr * 256 + ((((hseg >> 2)) ^ (kr & 31)) << 3);
  const unsigned short* const bsrc0 = Bexp + (b * 512 + kr) * 128 + hseg;

  // wave-uniform bases for scalar loads of A rows and v
  const int rf0 = __builtin_amdgcn_readfirstlane((b * 512 + qbase + rp * 2) * 128);
  const float4* const ar0 = (const float4*)(Aexp + rf0);
  const float4* const ar1 = ar0 + 32;  // next row (+128 floats)
  const float4* const vv4 = (const float4*)vw;

  uint4 stg[8];
#define K2_LOADS(kt_)                                                     \
  {                                                                       \
    const uint4* s_ = (const uint4*)(bsrc0 + (kt_) * 16384);              \
    _Pragma("unroll") for (int j = 0; j < 8; ++j) stg[j] = s_[j];         \
  }
#define K2_WRITE()                                                        \
  {                                                                       \
    _Pragma("unroll") for (int j = 0; j < 8; ++j) {                       \
      int off_ = woff0 ^ (j << 4);                                        \
      *(uint2*)(Bt_raw + off_) = make_uint2(stg[j].x, stg[j].y);          \
      *(uint2*)(Bt_raw + (off_ ^ 8)) = make_uint2(stg[j].z, stg[j].w);    \
    }                                                                     \
  }

  K2_LOADS(0);
  K2_WRITE();
  __syncthreads();

  float S0[4], S1[4];
#pragma unroll
  for (int kt = 0; kt < 4; ++kt) {
    if (kt < 3) K2_LOADS(kt + 1);  // in flight under compute
    float s0 = 0.f, s1 = 0.f;
#pragma unroll 8
    for (int hg = 0; hg < 32; ++hg) {
      unsigned long long u =
          *(const unsigned long long*)(Bt_raw + (roff0 ^ (hg << 3)));
      float4 v4 = vv4[hg];  // scalar (uniform)
      float4 a0 = ar0[hg];  // scalar (uniform)
      float4 a1 = ar1[hg];  // scalar (uniform)
      unsigned int lo = (unsigned int)u, hi = (unsigned int)(u >> 32);
      float b0 = __uint_as_float(lo << 16);
      float b1 = __uint_as_float(lo & 0xffff0000u);
      float b2 = __uint_as_float(hi << 16);
      float b3 = __uint_as_float(hi & 0xffff0000u);
      {  // row 0: sum_{i=0..3} v_i/x_i with ONE rcp
        float x0 = fmaf(a0.x, b0, 1.f), x1 = fmaf(a0.y, b1, 1.f);
        float x2 = fmaf(a0.z, b2, 1.f), x3 = fmaf(a0.w, b3, 1.f);
        float p01 = x0 * x1, p23 = x2 * x3;
        float n01 = fmaf(v4.x, x1, v4.y * x0);
        float n23 = fmaf(v4.z, x3, v4.w * x2);
        float num = fmaf(n01, p23, n23 * p01);
        s0 = fmaf(num, frcp(p01 * p23), s0);
      }
      {  // row 1
        float x0 = fmaf(a1.x, b0, 1.f), x1 = fmaf(a1.y, b1, 1.f);
        float x2 = fmaf(a1.z, b2, 1.f), x3 = fmaf(a1.w, b3, 1.f);
        float p01 = x0 * x1, p23 = x2 * x3;
        float n01 = fmaf(v4.x, x1, v4.y * x0);
        float n23 = fmaf(v4.z, x3, v4.w * x2);
        float num = fmaf(n01, p23, n23 * p01);
        s1 = fmaf(num, frcp(p01 * p23), s1);
      }
    }
    S0[kt] = s0;
    S1[kt] = s1;
    if (kt < 3) {
      __syncthreads();  // all reads of Bt done
      K2_WRITE();       // vmcnt wait inserted by compiler
      __syncthreads();  // Bt ready
    }
  }
#undef K2_LOADS
#undef K2_WRITE

  // softmax over k of (-2S): max(score) <-> min(S). Rows span 2 waves (k-halves).
  float mn0 = fminf(fminf(S0[0], S0[1]), fminf(S0[2], S0[3]));
  float mn1 = fminf(fminf(S1[0], S1[1]), fminf(S1[2], S1[3]));
#pragma unroll
  for (int off = 32; off > 0; off >>= 1) {
    mn0 = fminf(mn0, __shfl_xor(mn0, off));
    mn1 = fminf(mn1, __shfl_xor(mn1, off));
  }
  if (lane == 0) { red[wav][0] = mn0; red[wav][1] = mn1; }
  __syncthreads();
  mn0 = fminf(red[wav][0], red[wav ^ 1][0]);
  mn1 = fminf(red[wav][1], red[wav ^ 1][1]);
  __syncthreads();  // before red reuse

  float P0[4], P1[4];
  float sum0 = 0.f, sum1 = 0.f;
#pragma unroll
  for (int kt = 0; kt < 4; ++kt) {
    P0[kt] = fexp2((mn0 - S0[kt]) * TWO_LOG2E);
    P1[kt] = fexp2((mn1 - S1[kt]) * TWO_LOG2E);
    sum0 += P0[kt];
    sum1 += P1[kt];
  }
#pragma unroll
  for (int off = 32; off > 0; off >>= 1) {
    sum0 += __shfl_xor(sum0, off);
    sum1 += __shfl_xor(sum1, off);
  }
  if (lane == 0) { red[wav][0] = sum0; red[wav][1] = sum1; }
  __syncthreads();
  float r0 = frcp(red[wav][0] + red[wav ^ 1][0]);
  float r1 = frcp(red[wav][1] + red[wav ^ 1][1]);

  const int row0 = (b * 512 + qbase + rp * 2) * 512;
#pragma unroll
  for (int kt = 0; kt < 4; ++kt) {
    int kcol = kt * 128 + kh * 64 + lane;
    attn[row0 + kcol] = P0[kt] * r0;
    attn[row0 + 512 + kcol] = P1[kt] * r1;
  }
}

// ---------------------------------------------------------------------------
// K3: context[b] = attn[b] @ value[b] via bf16 MFMA 16x16x32.
// Tile 64x64, BK=64, 4 waves (2x2), wave tile 32x32 (2x2 frags).
// grid (8,8,8), block 256.
// ---------------------------------------------------------------------------
__global__ __launch_bounds__(256) void k_context_mfma(
    const float* __restrict__ attn, const unsigned short* __restrict__ valT,
    float* __restrict__ ctx) {
  __shared__ __align__(16) char At[64 * 128];  // [m][k] bf16 swizzled, 8KB
  __shared__ __align__(16) char Bt[64 * 128];  // [n][k] bf16 swizzled, 8KB

  const int t = threadIdx.x;
  const int b = blockIdx.z;
  const int m0 = blockIdx.y * 64, n0 = blockIdx.x * 64;
  const int w = t >> 6, l = t & 63;
  const int wr = w >> 1, wc = w & 1;

  f32x4v acc[2][2];
  acc[0][0] = 0; acc[0][1] = 0; acc[1][0] = 0; acc[1][1] = 0;

  const int sr = t >> 2;
  const int sg = (t & 3);
  const int sswz = sr & 7;

  for (int k0 = 0; k0 < 512; k0 += 64) {
    if (k0) __syncthreads();
    {  // stage A: 16 f32 -> 16 bf16 per thread
      const float* src = &attn[(b * 512 + m0 + sr) * 512 + k0 + sg * 16];
      char* dst = At + sr * 128;
#pragma unroll
      for (int h = 0; h < 2; ++h) {
        float4 f0 = *(const float4*)(src + h * 8);
        float4 f1 = *(const float4*)(src + h * 8 + 4);
        uint4 p = make_uint4(pack2bf(f0.x, f0.y), pack2bf(f0.z, f0.w),
                             pack2bf(f1.x, f1.y), pack2bf(f1.z, f1.w));
        int g = sg * 2 + h;
        *(uint4*)(dst + ((g ^ sswz) << 4)) = p;
      }
      // stage B^T: 32 bf16 per thread (already bf16)
      const unsigned short* srcb = &valT[(b * 512 + n0 + sr) * 512 + k0];
      char* dstb = Bt + sr * 128;
#pragma unroll
      for (int h = 0; h < 2; ++h) {
        int g = sg + h * 4;
        uint4 vb = *(const uint4*)(srcb + g * 8);
        *(uint4*)(dstb + ((g ^ sswz) << 4)) = vb;
      }
    }
    __syncthreads();
#pragma unroll
    for (int ks = 0; ks < 2; ++ks) {
      const int gb = ks * 4 + (l >> 4);
      short8 af[2], bf_[2];
#pragma unroll
      for (int mi = 0; mi < 2; ++mi) {
        int ra = wr * 32 + mi * 16 + (l & 15);
        af[mi] = *(const short8*)(At + ra * 128 + ((gb ^ (ra & 7)) << 4));
      }
#pragma unroll
      for (int ni = 0; ni < 2; ++ni) {
        int rb = wc * 32 + ni * 16 + (l & 15);
        bf_[ni] = *(const short8*)(Bt + rb * 128 + ((gb ^ (rb & 7)) << 4));
      }
#pragma unroll
      for (int mi = 0; mi < 2; ++mi)
#pragma unroll
        for (int ni = 0; ni < 2; ++ni)
          acc[mi][ni] = __builtin_amdgcn_mfma_f32_16x16x32_bf16(
              af[mi], bf_[ni], acc[mi][ni], 0, 0, 0);
    }
  }
  __syncthreads();
#pragma unroll
  for (int mi = 0; mi < 2; ++mi)
#pragma unroll
    for (int ni = 0; ni < 2; ++ni) {
      int col = n0 + wc * 32 + ni * 16 + (l & 15);
#pragma unroll
      for (int j = 0; j < 4; ++j) {
        int row = m0 + wr * 32 + mi * 16 + (l >> 4) * 4 + j;
        ctx[(b * 512 + row) * 512 + col] = acc[mi][ni][j];
      }
    }
}

extern "C" void kernel_launch(void* const* d_in, const int* in_sizes, int n_in,
                              void* d_out, int out_size, void* d_ws, size_t ws_size,
                              hipStream_t stream) {
  const float* query = (const float*)d_in[0];
  const float* key   = (const float*)d_in[1];
  const float* value = (const float*)d_in[2];
  const float* w1    = (const float*)d_in[3];
  const float* w2    = (const float*)d_in[4];
  const float* v     = (const float*)d_in[5];

  float* attn = (float*)d_out;
  float* ctx  = attn + 8 * 512 * 512;

  float* Aexp = (float*)d_ws;                                   // 4096*128 f32
  unsigned short* Bexp = (unsigned short*)(Aexp + 4096 * 128);  // 4096*128 bf16
  unsigned short* valT = Bexp + 4096 * 128;                     // 8*512*512 bf16

  k_proj_mfma<<<dim3(128, 2, 2), 256, 0, stream>>>(query, key, w1, w2, Aexp, Bexp);
  k_valT<<<dim3(8, 8, 8), 256, 0, stream>>>(value, valT);
  k_score_softmax<<<dim3(128, 8), 256, 0, stream>>>(Aexp, Bexp, v, attn);
  k_context_mfma<<<dim3(8, 8, 8), 256, 0, stream>>>(attn, valT, ctx);
}